// Round 5
// baseline (173.336 us; speedup 1.0000x reference)
//
#include <hip/hip_runtime.h>
#include <stdint.h>

typedef __attribute__((ext_vector_type(8))) short short8;
typedef __attribute__((ext_vector_type(4))) float f32x4;
typedef __attribute__((ext_vector_type(16))) float f32x16;
typedef __attribute__((ext_vector_type(4))) float float4v;
typedef __attribute__((ext_vector_type(4))) unsigned short u16x4;
typedef __attribute__((ext_vector_type(8))) unsigned short u16x8;

#define AS1 __attribute__((address_space(1)))
#define AS3 __attribute__((address_space(3)))

// B=4, C=512, Lf=8192, A=6. N = 49152.
// d_out: obj [4][49152] @0, reg [4][49152][2] @196608, anchors [49152][2] @589824.
// ws layout (bytes):
//   wAf   @ 0        : bf16 conv weights pre-fragmented for 32x32x16 MFMA.
//                      chunk id = (cb32*3+t)*32+ks (cb32: 32-cout block, ks:
//                      16-cin step); 512 elems/chunk; lane i holds
//                      A[cout=cb32*32+(i&31)][cin=ks*16+(i>>5)*8 .. +8] (1,572,864)
//   hwp   @ 1572864  : bf16 [32][512], rows 0-5 obj_w, 6-17 reg_w, rest 0 (32,768)
//   featT @ 1605632  : bf16 [4][8208][512], row r holds l=r-1;
//                      rows 0 and 8193 zeroed (SAME pad), 8194+ slop (33,619,968)
//   part  @ 35225600 : fp32 [4 mblk][4 b][8192 l][18 j] head partials (9,437,184)

__device__ __forceinline__ unsigned short f2bf(float f) {
    union { float f; unsigned int u; } v; v.f = f;
    unsigned int r = v.u + 0x7fffu + ((v.u >> 16) & 1u);
    return (unsigned short)(r >> 16);
}

__constant__ float c_AL[6] = {2.f, 4.f, 6.f, 9.f, 13.f, 18.f};

// blocks [0,4096): 64x64 transpose tiles.  blocks [4096,7440): prep work.
__global__ __launch_bounds__(256) void prep_transpose_kernel(
    const float* __restrict__ feat, const float* __restrict__ conv_w,
    const float* __restrict__ obj_w, const float* __restrict__ reg_w,
    unsigned short* __restrict__ wAf, unsigned short* __restrict__ hwp,
    unsigned short* __restrict__ featT, float* __restrict__ out) {
    __shared__ unsigned short tile[64][68];   // bf16 [c][l], pad 68
    unsigned int bx = blockIdx.x;
    int tid = threadIdx.x;
    if (bx < 4096u) {
        int l0 = (bx & 127) * 64, c0 = ((bx >> 7) & 7) * 64, b = bx >> 10;
        const float* fb = feat + ((size_t)b * 512 + c0) * 8192 + l0;
        #pragma unroll
        for (int it = 0; it < 4; ++it) {
            int slot = it * 256 + tid;
            int c = slot >> 4, l4 = (slot & 15) << 2;
            float4v v = *(const float4v*)(fb + (size_t)c * 8192 + l4);
            u16x4 pk;
            pk.x = f2bf(v.x); pk.y = f2bf(v.y);
            pk.z = f2bf(v.z); pk.w = f2bf(v.w);
            *(u16x4*)(&tile[c][l4]) = pk;
        }
        __syncthreads();
        unsigned short* ftb = featT + ((size_t)b * 8208 + 1 + l0) * 512 + c0;
        #pragma unroll
        for (int it = 0; it < 2; ++it) {
            int slot = it * 256 + tid;
            int l = slot >> 3, c8 = (slot & 7) << 3;
            u16x8 pk;
            #pragma unroll
            for (int j = 0; j < 8; ++j) pk[j] = tile[c8 + j][l];
            *(u16x8*)(ftb + (size_t)l * 512 + c8) = pk;
        }
        return;
    }
    unsigned int idx = (bx - 4096u) * 256 + tid;
    if (idx < 786432u) {
        // fragment-major conv weights for 32x32x16
        unsigned int chunkid = idx >> 9;            // 0..1535
        unsigned int within = idx & 511u;
        unsigned int lane = within >> 3, j = within & 7u;
        unsigned int ks = chunkid & 31u;
        unsigned int v = chunkid >> 5;              // cb32*3 + t
        unsigned int t = v % 3u, cb32 = v / 3u;
        unsigned int cout = cb32 * 32u + (lane & 31u);
        unsigned int cin = ks * 16u + (lane >> 5) * 8u + j;
        wAf[idx] = f2bf(conv_w[(cout * 512u + cin) * 3u + t]);
    } else if (idx < 802816u) {
        unsigned int i2 = idx - 786432u;
        unsigned int j = i2 >> 9, c = i2 & 511u;
        float v = 0.f;
        if (j < 6u) v = obj_w[j * 512u + c];
        else if (j < 18u) v = reg_w[(j - 6u) * 512u + c];
        hwp[i2] = f2bf(v);
    } else if (idx < 851968u) {
        unsigned int n = idx - 802816u;
        unsigned int l = n / 6u, a = n - l * 6u;
        float ctr = (float)l + 0.5f, half = 0.5f * c_AL[a];
        float* anchors = out + 589824;
        anchors[2 * n]     = ctr - half;
        anchors[2 * n + 1] = ctr + half;
    } else if (idx < 856064u) {
        unsigned int i4 = idx - 851968u;
        unsigned int b = i4 >> 10, rem = i4 & 1023u;
        unsigned int row = (rem >> 9) ? 8193u : 0u;
        unsigned int c = rem & 511u;
        featT[((size_t)b * 8208 + row) * 512 + c] = 0;
    }
}

// Conv GEMM: per block, 128 couts x 128 l's, K = 3 taps * 512 cin.
// 32x32x16 bf16 MFMA: wave tile 64x64 = 2x2 frags; same LDS traffic as
// 16x16x32 but half the MFMA instructions at the faster 32x32 rate.
// Fragment-major LDS for A; B staged rows x 32cin. Epilogue: bias+relu ->
// bf16 htile in LDS, fused heads mini-GEMM -> per-mblock partials.
// launch_bounds(256,4): 4 blocks/CU (LDS 4*34816=139KB), grid 1024 = 4/CU.
__global__ __launch_bounds__(256, 4) void conv_gemm_kernel(
    const unsigned short* __restrict__ wAf,
    const unsigned short* __restrict__ featT,
    const float* __restrict__ conv_b,
    const unsigned short* __restrict__ hwp,
    float* __restrict__ part) {
    __shared__ unsigned short smem[17408];  // loop: 33*512 staging; epi: htile 128*136

    const int tid = threadIdx.x;
    const int wave = tid >> 6, lane = tid & 63;
    const int lq = lane >> 4, lr = lane & 15;
    const int l32 = lane & 31, lh = lane >> 5;
    const int l0 = blockIdx.x * 128;
    const int m0 = blockIdx.y * 128;
    const int b = blockIdx.z;
    const int wm = wave >> 1, wn = wave & 1;
    const unsigned short* ftb = featT + (size_t)b * 8208 * 512;

    f32x16 acc[2][2];
    #pragma unroll
    for (int i = 0; i < 2; ++i)
        #pragma unroll
        for (int j = 0; j < 2; ++j)
            #pragma unroll
            for (int r = 0; r < 16; ++r)
                acc[i][j][r] = 0.f;

    for (int kc = 0; kc < 16; ++kc) {
        __syncthreads();
        // 33 chunks of 1024B: 24 A-chunks + 9 B-chunks (144 rows x 32 cin)
        for (int ci = wave; ci < 33; ci += 4) {
            const unsigned short* g;
            if (ci < 24) {
                // ci = ((t*4+cb)*2+s): s=kstep half, cb=local 32-block, t=tap
                int s = ci & 1, u = ci >> 1;
                int cb = u & 3, t = u >> 2;
                g = wAf + ((size_t)(((m0 >> 5) + cb) * 3 + t) * 32 + kc * 2 + s) * 512
                    + lane * 8;
            } else {
                int lb = ci - 24;
                g = ftb + (size_t)(l0 + lb * 16 + lr) * 512 + kc * 32 + lq * 8;
            }
            __builtin_amdgcn_global_load_lds((const AS1 void*)g,
                                             (AS3 void*)(smem + ci * 512), 16, 0, 0);
        }
        __syncthreads();
        #pragma unroll
        for (int t = 0; t < 3; ++t) {
            #pragma unroll
            for (int s = 0; s < 2; ++s) {
                short8 af[2], bf[2];
                #pragma unroll
                for (int fm = 0; fm < 2; ++fm) {
                    int ci = ((t * 4 + wm * 2 + fm) * 2 + s);
                    af[fm] = *(const short8*)(smem + (ci << 9) + (lane << 3));
                }
                #pragma unroll
                for (int fn = 0; fn < 2; ++fn) {
                    int R = wn * 64 + fn * 32 + l32 + t;      // tap-shifted B row
                    int q = s * 2 + lh;                        // 8-col group
                    bf[fn] = *(const short8*)(smem + ((24 + (R >> 4)) << 9) +
                                              (((q << 4) | (R & 15)) << 3));
                }
                #pragma unroll
                for (int fm = 0; fm < 2; ++fm)
                    #pragma unroll
                    for (int fn = 0; fn < 2; ++fn)
                        acc[fm][fn] = __builtin_amdgcn_mfma_f32_32x32x16_bf16(
                            af[fm], bf[fn], acc[fm][fn], 0, 0, 0);
            }
        }
    }
    __syncthreads();
    // epilogue 1: bias + relu -> bf16 htile [l][cout], row stride 136.
    // 32x32 C layout: n(l) = lane&31, m = (reg&3) + 8*(reg>>2) + 4*(lane>>5)
    #pragma unroll
    for (int fm = 0; fm < 2; ++fm) {
        #pragma unroll
        for (int fn = 0; fn < 2; ++fn) {
            int l = wn * 64 + fn * 32 + l32;
            #pragma unroll
            for (int rq = 0; rq < 4; ++rq) {
                int mb = wm * 64 + fm * 32 + rq * 8 + lh * 4;
                float cb0 = conv_b[m0 + mb];
                float cb1 = conv_b[m0 + mb + 1];
                float cb2 = conv_b[m0 + mb + 2];
                float cb3 = conv_b[m0 + mb + 3];
                u16x4 pk;
                pk.x = f2bf(fmaxf(acc[fm][fn][rq * 4 + 0] + cb0, 0.f));
                pk.y = f2bf(fmaxf(acc[fm][fn][rq * 4 + 1] + cb1, 0.f));
                pk.z = f2bf(fmaxf(acc[fm][fn][rq * 4 + 2] + cb2, 0.f));
                pk.w = f2bf(fmaxf(acc[fm][fn][rq * 4 + 3] + cb3, 0.f));
                *(u16x4*)(smem + l * 136 + mb) = pk;
            }
        }
    }
    __syncthreads();
    // epilogue 2: fused heads (16x16x32). Per wave: 32 l x 32 j x K=128 couts.
    f32x4 hacc[2][2];
    #pragma unroll
    for (int i = 0; i < 2; ++i) {
        hacc[i][0] = (f32x4){0.f, 0.f, 0.f, 0.f};
        hacc[i][1] = (f32x4){0.f, 0.f, 0.f, 0.f};
    }
    const int lbase = wave * 32;
    for (int kk = 0; kk < 4; ++kk) {
        short8 ha[2], hb2[2];
        #pragma unroll
        for (int fm2 = 0; fm2 < 2; ++fm2)
            ha[fm2] = *(const short8*)(smem + (lbase + fm2 * 16 + lr) * 136 + kk * 32 + lq * 8);
        #pragma unroll
        for (int fn = 0; fn < 2; ++fn)
            hb2[fn] = *(const short8*)(hwp + (size_t)(fn * 16 + lr) * 512 + m0 + kk * 32 + lq * 8);
        #pragma unroll
        for (int fm2 = 0; fm2 < 2; ++fm2)
            #pragma unroll
            for (int fn = 0; fn < 2; ++fn)
                hacc[fm2][fn] = __builtin_amdgcn_mfma_f32_16x16x32_bf16(
                    ha[fm2], hb2[fn], hacc[fm2][fn], 0, 0, 0);
    }
    // partials store: part[mblk=by][b][l][j]
    float* pb = part + ((size_t)(blockIdx.y * 4 + b) * 8192) * 18;
    #pragma unroll
    for (int fn = 0; fn < 2; ++fn) {
        int j = fn * 16 + lr;
        if (j >= 18) continue;
        #pragma unroll
        for (int fm2 = 0; fm2 < 2; ++fm2)
            #pragma unroll
            for (int r = 0; r < 4; ++r) {
                int l = l0 + lbase + fm2 * 16 + lq * 4 + r;
                pb[(size_t)l * 18 + j] = hacc[fm2][fn][r];
            }
    }
}

__global__ __launch_bounds__(256) void reduce_kernel(
    const float* __restrict__ part, const float* __restrict__ obj_b,
    const float* __restrict__ reg_b, float* __restrict__ out) {
    unsigned int idx = blockIdx.x * 256 + threadIdx.x;
    if (idx >= 589824u) return;
    unsigned int j = idx % 18u;
    unsigned int t = idx / 18u;
    unsigned int l = t & 8191u;
    unsigned int b = t >> 13;
    float s = 0.f;
    #pragma unroll
    for (int mb = 0; mb < 4; ++mb)
        s += part[((size_t)(mb * 4 + b) * 8192 + l) * 18 + j];
    if (j < 6u) {
        s += obj_b[j];
        out[(size_t)b * 49152 + l * 6 + j] = s;
    } else {
        s += reg_b[j - 6u];
        out[196608u + (size_t)b * 98304 + l * 12 + (j - 6u)] = s;
    }
}

extern "C" void kernel_launch(void* const* d_in, const int* in_sizes, int n_in,
                              void* d_out, int out_size, void* d_ws, size_t ws_size,
                              hipStream_t stream) {
    const float* feat   = (const float*)d_in[0];
    const float* conv_w = (const float*)d_in[1];
    const float* conv_b = (const float*)d_in[2];
    const float* obj_w  = (const float*)d_in[3];
    const float* obj_b  = (const float*)d_in[4];
    const float* reg_w  = (const float*)d_in[5];
    const float* reg_b  = (const float*)d_in[6];
    float* out = (float*)d_out;
    char* ws = (char*)d_ws;
    unsigned short* wAf   = (unsigned short*)(ws);
    unsigned short* hwp   = (unsigned short*)(ws + 1572864);
    unsigned short* featT = (unsigned short*)(ws + 1605632);
    float* part           = (float*)(ws + 35225600);

    prep_transpose_kernel<<<dim3(7440), dim3(256), 0, stream>>>(
        feat, conv_w, obj_w, reg_w, wAf, hwp, featT, out);
    conv_gemm_kernel<<<dim3(64, 4, 4), dim3(256), 0, stream>>>(wAf, featT, conv_b, hwp, part);
    reduce_kernel<<<dim3(2304), dim3(256), 0, stream>>>(part, obj_b, reg_b, out);
}